// Round 1
// baseline (132.145 us; speedup 1.0000x reference)
//
#include <hip/hip_runtime.h>

// Orbitals_ent: sorted-occupancy gather.
// x: (2048, 256) int32 in {-1,+1}
// orbitals_mf: (512, 256) f32, orbitals_hf: (512, 64) f32
// out: (2048, 256, 320) f32 = orbitals_full[idx] with idx = ascending indices
// of occupied spin-orbitals (ups first, then downs, each ascending by site).

#define NBATCH 2048
#define NS 256   // sites (= rows gathered per batch)
#define NMF 256  // mf columns
#define NHF 64   // hf columns
#define NROW 320 // NMF + NHF

__global__ __launch_bounds__(256) void gather_orbitals(
    const int* __restrict__ x,
    const float* __restrict__ mf,
    const float* __restrict__ hf,
    float* __restrict__ out)
{
    __shared__ int src[NS];   // dest row -> source spin-orbital row
    __shared__ int wtot[4];   // per-wave up counts

    const int b    = blockIdx.x;
    const int tid  = threadIdx.x;
    const int wave = tid >> 6;
    const int lane = tid & 63;

    // --- build dest->src permutation via prefix-sum of up-occupancy ---
    const int xv = x[(size_t)b * NS + tid];
    const bool up = (xv == 1);
    const unsigned long long m = __ballot(up);             // 64-bit on CDNA
    const int lane_ex = __popcll(m & ((1ull << lane) - 1ull));
    if (lane == 0) wtot[wave] = __popcll(m);
    __syncthreads();

    int woff = 0, nup = 0;
#pragma unroll
    for (int w = 0; w < 4; ++w) {
        const int c = wtot[w];
        if (w < wave) woff += c;
        nup += c;
    }
    const int upex = woff + lane_ex;          // #ups among sites < tid
    const int dest = up ? upex : (nup + (tid - upex));
    src[dest] = up ? tid : (NS + tid);
    __syncthreads();

    float* outb = out + (size_t)b * NS * NROW;

    // --- mf part: one wave per output row; 64 lanes x float4 = 256 floats ---
    for (int r = wave; r < NS; r += 4) {
        const int s = src[r];
        const float4 v = ((const float4*)(mf + (size_t)s * NMF))[lane];
        ((float4*)(outb + (size_t)r * NROW))[lane] = v;
    }

    // --- hf part: 16 lanes per row; 16 x float4 = 64 floats ---
    const int r16 = tid >> 4;
    const int l16 = tid & 15;
    for (int r = r16; r < NS; r += 16) {
        const int s = src[r];
        const float4 v = ((const float4*)(hf + (size_t)s * NHF))[l16];
        ((float4*)(outb + (size_t)r * NROW + NMF))[l16] = v;
    }
}

extern "C" void kernel_launch(void* const* d_in, const int* in_sizes, int n_in,
                              void* d_out, int out_size, void* d_ws, size_t ws_size,
                              hipStream_t stream) {
    const int*   x  = (const int*)d_in[0];
    const float* mf = (const float*)d_in[1];
    const float* hf = (const float*)d_in[2];
    float* out = (float*)d_out;

    gather_orbitals<<<dim3(NBATCH), dim3(256), 0, stream>>>(x, mf, hf, out);
}